// Round 7
// baseline (322.979 us; speedup 1.0000x reference)
//
#include <hip/hip_runtime.h>

#define MDIM 8192
#define NDIM 4096
#define KDIM 4096

typedef __attribute__((ext_vector_type(8))) short short8;
typedef __attribute__((ext_vector_type(4))) float f32x4;
typedef unsigned short u16;
typedef unsigned int u32;

__device__ __forceinline__ u16 f2bf(float f) {
  return __builtin_bit_cast(u16, static_cast<__bf16>(f));
}

// ---------------- prepass 1: x f32 -> bf16 ----------------
__global__ __launch_bounds__(256) void cvt_x_kernel(const float* __restrict__ x,
                                                    u16* __restrict__ xb, int n8) {
  const int stride = gridDim.x * 256;
  for (int u = blockIdx.x * 256 + threadIdx.x; u < n8; u += stride) {
    const float* p = x + (size_t)u * 8;
    const f32x4 a = *(const f32x4*)p;
    const f32x4 b = *(const f32x4*)(p + 4);
    short8 v;
#pragma unroll
    for (int j = 0; j < 4; ++j) {
      v[j]     = (short)f2bf(a[j]);
      v[4 + j] = (short)f2bf(b[j]);
    }
    *(short8*)(xb + (size_t)u * 8) = v;
  }
}

// ---------------- prepass 2: dequant qweight once -> Wt[n][k] bf16 ----------------
__global__ __launch_bounds__(256) void dequant_w_kernel(const int* __restrict__ qw,
                                                        const int* __restrict__ qz,
                                                        const float* __restrict__ sc,
                                                        u16* __restrict__ wt) {
  const int g = blockIdx.x * 256 + threadIdx.x;
  const int n = g & (NDIM - 1);
  const int kp0 = (g >> 12) * 4;
  const float s = sc[n];
  const int zw = qz[n >> 3];
  const int zp1 = ((zw >> ((n & 7) * 4)) & 0xF) + 1;
  const float sz = -(float)zp1 * s;
#pragma unroll
  for (int i = 0; i < 4; ++i) {
    const int w = qw[(size_t)(kp0 + i) * NDIM + n];
    short8 v;
#pragma unroll
    for (int j = 0; j < 8; ++j)
      v[j] = (short)f2bf(fmaf((float)((w >> (4 * j)) & 0xF), s, sz));
    *(short8*)(wt + (size_t)n * KDIM + (size_t)(kp0 + i) * 8) = v;
  }
}

// ---------------- main GEMM: 256x256, 8 phases, deep-slack counted vmcnt ----------------
// Ledger (steady, per iter i, tiles t=2i->buf0, t+1->buf1; 1 half-tile staged/phase):
//   p1: B1(t+1)   vm4 (forces A-Y(t))      p5: B1(t+2)   vm4 (forces A-Y(t+1))
//   p2: A-X(t+1)                           p6: A-X(t+2)
//   p3: A-Y(t+1)  vm2 (forces B+AX(t+1))   p7: A-Y(t+2)  vm2 (forces B+AX(t+2))
//   p4: B0(t+2)   [RDB(t+1) after QMF]     p8: B0(t+3)   [RDB(t+2) after QMF]
// A-X = LDS rows [0,63]u[128,191] (quads 0,1 both wave-rows); A-Y = rows [64,127]u[192,255].

#define BAR()    __builtin_amdgcn_s_barrier()
#define FENCE()  __builtin_amdgcn_sched_barrier(0)
#define VM2()    asm volatile("s_waitcnt vmcnt(2)" ::: "memory")
#define VM4()    asm volatile("s_waitcnt vmcnt(4)" ::: "memory")
#define PRIO1()  __builtin_amdgcn_s_setprio(1)
#define PRIO0()  __builtin_amdgcn_s_setprio(0)

// stage one half-tile: rows {R0..R0+63} and {R1..R1+63} of buf, K-tile T
#define STG2(PBASE, LDSBASE, BUF, T, R0, R1) do {                             \
    __builtin_amdgcn_global_load_lds(                                         \
      (const __attribute__((address_space(1))) void*)                         \
        (PBASE + (size_t)(R0) * KDIM + (T) * 64),                             \
      (__attribute__((address_space(3))) void*)                               \
        (LDSBASE + (BUF) * 32768 + (R0) * 128 + tid * 16), 16, 0, 0);         \
    __builtin_amdgcn_global_load_lds(                                         \
      (const __attribute__((address_space(1))) void*)                         \
        (PBASE + (size_t)(R1) * KDIM + (T) * 64),                             \
      (__attribute__((address_space(3))) void*)                               \
        (LDSBASE + (BUF) * 32768 + (R1) * 128 + tid * 16), 16, 0, 0);         \
  } while (0)

#define RDB(BUF) do {                                                         \
    _Pragma("unroll")                                                         \
    for (int nf_ = 0; nf_ < 4; ++nf_) {                                       \
      const char* r_ = BsB + (BUF) * 32768 + (wcol * 64 + nf_ * 16 + lr) * 128;\
      b[nf_][0] = *(const short8*)(r_ + ua0);                                 \
      b[nf_][1] = *(const short8*)(r_ + ua1);                                 \
    }                                                                         \
  } while (0)

#define RDA_(BUF, MF0, DST) do {                                              \
    _Pragma("unroll")                                                         \
    for (int i_ = 0; i_ < 2; ++i_) {                                          \
      const char* r_ = AsB + (BUF) * 32768 + (wrow * 128 + ((MF0) + i_) * 16 + lr) * 128; \
      DST[i_][0] = *(const short8*)(r_ + ua0);                                \
      DST[i_][1] = *(const short8*)(r_ + ua1);                                \
    }                                                                         \
  } while (0)

#define QMF_(MF0, SRC) do {                                                   \
    _Pragma("unroll")                                                         \
    for (int ks_ = 0; ks_ < 2; ++ks_)                                         \
      _Pragma("unroll")                                                       \
      for (int i_ = 0; i_ < 2; ++i_)                                          \
        _Pragma("unroll")                                                     \
        for (int nf_ = 0; nf_ < 4; ++nf_)                                     \
          acc[(MF0) + i_][nf_] = __builtin_amdgcn_mfma_f32_16x16x32_bf16(     \
              SRC[i_][ks_], b[nf_][ks_], acc[(MF0) + i_][nf_], 0, 0, 0);      \
  } while (0)

__global__ __launch_bounds__(512, 2) void qgemm_bf16_8ph(const u16* __restrict__ A,
                                                         const u16* __restrict__ Bt,
                                                         float* __restrict__ out) {
  __shared__ __align__(16) char AsB[2 * 32768];  // [buf][256 rows][64 k] bf16
  __shared__ __align__(16) char BsB[2 * 32768];

  const int tid  = threadIdx.x;
  const int lane = tid & 63;
  const int wave = tid >> 6;
  const int wrow = wave >> 2;  // 0..1
  const int wcol = wave & 3;   // 0..3

  const int bid = blockIdx.x;
  const int sb = bid >> 4, li = bid & 15;
  const int mb = (sb & 7) * 4 + (li & 3);    // 0..31
  const int nb = (sb >> 3) * 4 + (li >> 2);  // 0..15
  const int m0 = mb * 256, n0 = nb * 256;

  // staging base (pre-swizzled involution: LDS slot u holds global unit u^(row&7);
  // row offsets in STG2 are multiples of 64 so the swizzle term is offset-invariant)
  const int srow  = tid >> 3;                 // 0..63
  const int sunit = (tid & 7) ^ (srow & 7);
  const u16* pAb = A  + (size_t)(m0 + srow) * KDIM + sunit * 8;
  const u16* pBb = Bt + (size_t)(n0 + srow) * KDIM + sunit * 8;

  const int lr = lane & 15;
  const int kh = lane >> 4;
  const int lx = lr & 7;
  const int ua0 = ((kh) ^ lx) * 16;      // ks=0 swizzled unit byte-offset
  const int ua1 = ((4 + kh) ^ lx) * 16;  // ks=1

  f32x4 acc[8][4];
#pragma unroll
  for (int i = 0; i < 8; ++i)
#pragma unroll
    for (int j = 0; j < 4; ++j)
      acc[i][j] = (f32x4)(0.f);

  short8 a2A[2][2], a2B[2][2];
  short8 b[4][2];

  // ---- prologue: tile0 (B0,B1,A-X,A-Y)->buf0, B0(1)->buf1; vm2 forces tile0 ----
  STG2(pBb, BsB, 0, 0, 0, 64);
  STG2(pBb, BsB, 0, 0, 128, 192);
  STG2(pAb, AsB, 0, 0, 0, 128);
  STG2(pAb, AsB, 0, 0, 64, 192);
  STG2(pBb, BsB, 1, 1, 0, 64);
  VM2();
  BAR(); FENCE();
  RDB(0);
  RDA_(0, 0, a2A);

  // ---- main loop: 32 iters x 2 K-tiles ----
  for (int i = 0; i < 32; ++i) {
    const int t1 = 2 * i + 1;
    const int t2 = (2 * i + 2) & 63;  // wraps harmlessly on last iter
    const int t3 = (2 * i + 3) & 63;

    // p1: MFMA q0(t) | rd q1 | stage B1(t+1)->buf1 | vm4 -> A-Y(t) landed
    STG2(pBb, BsB, 1, t1, 128, 192);
    RDA_(0, 2, a2B);
    PRIO1(); QMF_(0, a2A); PRIO0(); VM4(); FENCE(); BAR(); FENCE();
    // p2: q1 | rd q2 | stage A-X(t+1)->buf1
    STG2(pAb, AsB, 1, t1, 0, 128);
    RDA_(0, 4, a2A);
    PRIO1(); QMF_(2, a2B); PRIO0(); FENCE(); BAR(); FENCE();
    // p3: q2 | rd q3 | stage A-Y(t+1)->buf1 | vm2 -> B0,B1,A-X(t+1) landed
    STG2(pAb, AsB, 1, t1, 64, 192);
    RDA_(0, 6, a2B);
    PRIO1(); QMF_(4, a2A); PRIO0(); VM2(); FENCE(); BAR(); FENCE();
    // p4: q3(t) | rd q0(t+1) | stage B0(t+2)->buf0 | RDB(t+1) after QMF
    STG2(pBb, BsB, 0, t2, 0, 64);
    RDA_(1, 0, a2A);
    PRIO1(); QMF_(6, a2B); PRIO0(); RDB(1); FENCE(); BAR(); FENCE();
    // p5: q0(t+1) | rd q1 | stage B1(t+2)->buf0 | vm4 -> A-Y(t+1) landed
    STG2(pBb, BsB, 0, t2, 128, 192);
    RDA_(1, 2, a2B);
    PRIO1(); QMF_(0, a2A); PRIO0(); VM4(); FENCE(); BAR(); FENCE();
    // p6: q1 | rd q2 | stage A-X(t+2)->buf0
    STG2(pAb, AsB, 0, t2, 0, 128);
    RDA_(1, 4, a2A);
    PRIO1(); QMF_(2, a2B); PRIO0(); FENCE(); BAR(); FENCE();
    // p7: q2 | rd q3 | stage A-Y(t+2)->buf0 | vm2 -> B0,B1,A-X(t+2) landed
    STG2(pAb, AsB, 0, t2, 64, 192);
    RDA_(1, 6, a2B);
    PRIO1(); QMF_(4, a2A); PRIO0(); VM2(); FENCE(); BAR(); FENCE();
    // p8: q3(t+1) | rd q0(t+2) | stage B0(t+3)->buf1 | RDB(t+2) after QMF
    STG2(pBb, BsB, 1, t3, 0, 64);
    RDA_(0, 0, a2A);
    PRIO1(); QMF_(6, a2B); PRIO0(); RDB(0); FENCE(); BAR(); FENCE();
  }

  asm volatile("s_waitcnt vmcnt(0)" ::: "memory");  // drain trailing stages

  // ---- epilogue: C/D layout col=lane&15, row=(lane>>4)*4+reg ; out f32 ----
#pragma unroll
  for (int mf = 0; mf < 8; ++mf) {
#pragma unroll
    for (int nf = 0; nf < 4; ++nf) {
      const f32x4 c = acc[mf][nf];
      const int gc = n0 + wcol * 64 + nf * 16 + lr;
#pragma unroll
      for (int rg = 0; rg < 4; ++rg) {
        const int gr = m0 + wrow * 128 + mf * 16 + kh * 4 + rg;
        out[(size_t)gr * NDIM + gc] = c[rg];
      }
    }
  }
}

// ---------------- fallback: fused f32-input kernel (r3, proven) ----------------
#define BM 128
#define BN 128
#define BK 64
#define NKT (KDIM / BK)
#define LDA 72
__global__ __launch_bounds__(256) void qgemm_fused_f32(
    const float* __restrict__ x, const int* __restrict__ qweight,
    const int* __restrict__ qzeros, const float* __restrict__ scales,
    float* __restrict__ out) {
  __shared__ __align__(16) short As[BM * LDA];
  __shared__ __align__(16) short Bs[BN * LDA];

  const int tid = threadIdx.x;
  const int lane = tid & 63;
  const int wave = tid >> 6;
  const int wr = wave >> 1, wc = wave & 1;
  const int bid = blockIdx.x;
  const int sb = bid >> 4, li = bid & 15;
  const int mb = (sb & 15) * 4 + (li & 3);
  const int nb = (sb >> 4) * 4 + (li >> 2);
  const int m0 = mb * BM, n0 = nb * BN;

  const int ncol = tid & 127;
  const int kp_base = (tid >> 7) * 4;
  const int n_g = n0 + ncol;
  const float s = scales[n_g];
  const int zw = qzeros[n_g >> 3];
  const int zp1 = ((zw >> ((n_g & 7) * 4)) & 0xF) + 1;
  const float sz = -(float)zp1 * s;

  const int arow0 = tid >> 3;
  const int acol = (tid & 7) * 8;
  const int* qwp = qweight + (size_t)kp_base * NDIM + n_g;

  f32x4 af[8];
  {
    const float* xf = x + (size_t)(m0 + arow0) * KDIM + acol;
#pragma unroll
    for (int g = 0; g < 4; ++g) {
      af[2 * g]     = *(const f32x4*)(xf + (size_t)g * 32 * KDIM);
      af[2 * g + 1] = *(const f32x4*)(xf + (size_t)g * 32 * KDIM + 4);
    }
  }
  int qw0 = qwp[0], qw1 = qwp[NDIM], qw2 = qwp[2 * NDIM], qw3 = qwp[3 * NDIM];

  f32x4 acc[4][4];
#pragma unroll
  for (int i = 0; i < 4; ++i)
#pragma unroll
    for (int j = 0; j < 4; ++j)
      acc[i][j] = (f32x4)(0.f);

  const int lr = lane & 15, kh = lane >> 4;

  for (int kt = 0; kt < NKT; ++kt) {
    __syncthreads();
#pragma unroll
    for (int g = 0; g < 4; ++g) {
      short8 v;
#pragma unroll
      for (int j = 0; j < 4; ++j) {
        v[j]     = (short)f2bf(af[2 * g][j]);
        v[4 + j] = (short)f2bf(af[2 * g + 1][j]);
      }
      *(short8*)&As[(arow0 + g * 32) * LDA + acol] = v;
    }
    {
      const int qq[4] = {qw0, qw1, qw2, qw3};
#pragma unroll
      for (int r = 0; r < 4; ++r) {
        const int w = qq[r];
        short8 v;
#pragma unroll
        for (int j = 0; j < 8; ++j)
          v[j] = (short)f2bf(fmaf((float)((w >> (4 * j)) & 0xF), s, sz));
        *(short8*)&Bs[ncol * LDA + (kp_base + r) * 8] = v;
      }
    }
    if (kt + 1 < NKT) {
      const float* xp = x + (size_t)(m0 + arow0) * KDIM + (size_t)(kt + 1) * BK + acol;
#pragma unroll
      for (int g = 0; g < 4; ++g) {
        af[2 * g]     = *(const f32x4*)(xp + (size_t)g * 32 * KDIM);
        af[2 * g + 1] = *(const f32x4*)(xp + (size_t)g * 32 * KDIM + 4);
      }
      const int* p = qwp + (size_t)(kt + 1) * 8 * NDIM;
      qw0 = p[0]; qw1 = p[NDIM]; qw2 = p[2 * NDIM]; qw3 = p[3 * NDIM];
    }
    __syncthreads();
#pragma unroll
    for (int ks = 0; ks < 2; ++ks) {
      const int kb = (ks * 4 + kh) * 8;
      short8 a[4], bb[4];
#pragma unroll
      for (int mf = 0; mf < 4; ++mf)
        a[mf] = *(const short8*)&As[(wr * 64 + mf * 16 + lr) * LDA + kb];
#pragma unroll
      for (int nf = 0; nf < 4; ++nf)
        bb[nf] = *(const short8*)&Bs[(wc * 64 + nf * 16 + lr) * LDA + kb];
#pragma unroll
      for (int mf = 0; mf < 4; ++mf)
#pragma unroll
        for (int nf = 0; nf < 4; ++nf)
          acc[mf][nf] = __builtin_amdgcn_mfma_f32_16x16x32_bf16(a[mf], bb[nf], acc[mf][nf], 0, 0, 0);
    }
  }
#pragma unroll
  for (int mf = 0; mf < 4; ++mf)
#pragma unroll
    for (int nf = 0; nf < 4; ++nf) {
      const f32x4 c = acc[mf][nf];
      const int gc = n0 + wc * 64 + nf * 16 + lr;
#pragma unroll
      for (int rg = 0; rg < 4; ++rg)
        out[(size_t)(m0 + wr * 64 + mf * 16 + kh * 4 + rg) * NDIM + gc] = c[rg];
    }
}

extern "C" void kernel_launch(void* const* d_in, const int* in_sizes, int n_in,
                              void* d_out, int out_size, void* d_ws, size_t ws_size,
                              hipStream_t stream) {
  const float* x      = (const float*)d_in[0];  // fp16 ref stored as f32 on device
  const int* qweight  = (const int*)d_in[2];    // [K/8][N] int32
  const int* qzeros   = (const int*)d_in[3];    // [1][N/8] int32
  const float* scales = (const float*)d_in[4];  // fp16 ref stored as f32
  float* out = (float*)d_out;

  const size_t xb_bytes = (size_t)MDIM * KDIM * 2;  // 64 MB
  const size_t wt_bytes = (size_t)NDIM * KDIM * 2;  // 32 MB

  if (ws_size >= xb_bytes + wt_bytes) {
    u16* xb = (u16*)d_ws;
    u16* wt = (u16*)((char*)d_ws + xb_bytes);
    cvt_x_kernel<<<2048, 256, 0, stream>>>(x, xb, MDIM * KDIM / 8);
    dequant_w_kernel<<<2048, 256, 0, stream>>>(qweight, qzeros, scales, wt);
    const int grid = (MDIM / 256) * (NDIM / 256);  // 512
    qgemm_bf16_8ph<<<grid, 512, 0, stream>>>(xb, wt, out);
  } else {
    const int grid = (MDIM / BM) * (NDIM / BN);  // 2048
    qgemm_fused_f32<<<grid, 256, 0, stream>>>(x, qweight, qzeros, scales, out);
  }
}

// Round 8
// 304.508 us; speedup vs baseline: 1.0607x; 1.0607x over previous
//
#include <hip/hip_runtime.h>

#define MDIM 8192
#define NDIM 4096
#define KDIM 4096

typedef __attribute__((ext_vector_type(8))) short short8;
typedef __attribute__((ext_vector_type(4))) float f32x4;
typedef __attribute__((ext_vector_type(16))) float f32x16;
typedef unsigned short u16;
typedef unsigned int u32;

__device__ __forceinline__ u16 f2bf(float f) {
  return __builtin_bit_cast(u16, static_cast<__bf16>(f));
}

// ---------------- prepass 1: x f32 -> bf16 ----------------
__global__ __launch_bounds__(256) void cvt_x_kernel(const float* __restrict__ x,
                                                    u16* __restrict__ xb, int n8) {
  const int stride = gridDim.x * 256;
  for (int u = blockIdx.x * 256 + threadIdx.x; u < n8; u += stride) {
    const float* p = x + (size_t)u * 8;
    const f32x4 a = *(const f32x4*)p;
    const f32x4 b = *(const f32x4*)(p + 4);
    short8 v;
#pragma unroll
    for (int j = 0; j < 4; ++j) {
      v[j]     = (short)f2bf(a[j]);
      v[4 + j] = (short)f2bf(b[j]);
    }
    *(short8*)(xb + (size_t)u * 8) = v;
  }
}

// ---------------- prepass 2: dequant -> MFMA-fragment-linear Bp ----------------
// Bp layout: 16B unit index = nblk*16384 + kblk*64 + lane, holding
// W[n = nblk*32 + (lane&31)][k = kblk*16 + (lane>>5)*8 + e], e=0..7.
// A wave's 32x16 B-fragment = 64 consecutive units = 1KB contiguous.
__global__ __launch_bounds__(256) void dequant_w_kernel(const int* __restrict__ qw,
                                                        const int* __restrict__ qz,
                                                        const float* __restrict__ sc,
                                                        u16* __restrict__ wt) {
  const int g = blockIdx.x * 256 + threadIdx.x;  // 0..524287
  const int n = g & (NDIM - 1);
  const int kp0 = (g >> 12) * 4;
  const float s = sc[n];
  const int zw = qz[n >> 3];
  const int zp1 = ((zw >> ((n & 7) * 4)) & 0xF) + 1;
  const float sz = -(float)zp1 * s;
  const int nblk = n >> 5;
  const int lnlo = n & 31;
#pragma unroll
  for (int i = 0; i < 4; ++i) {
    const int kp = kp0 + i;
    const int w = qw[(size_t)kp * NDIM + n];
    short8 v;
#pragma unroll
    for (int j = 0; j < 8; ++j)
      v[j] = (short)f2bf(fmaf((float)((w >> (4 * j)) & 0xF), s, sz));
    const int kblk = kp >> 1;
    const int lane = ((kp & 1) << 5) + lnlo;
    const size_t unit = (size_t)nblk * 16384 + (size_t)kblk * 64 + lane;
    *(short8*)(wt + unit * 8) = v;
  }
}

// ---------------- main GEMM: 256x256, 32x32x16 MFMA, A 4-deep LDS, B from L2/L3 ----
#define BAR()    __builtin_amdgcn_s_barrier()
#define FENCE()  __builtin_amdgcn_sched_barrier(0)
#define VM4()    asm volatile("s_waitcnt vmcnt(4)" ::: "memory")
#define PRIO1()  __builtin_amdgcn_s_setprio(1)
#define PRIO0()  __builtin_amdgcn_s_setprio(0)

// stage full A-tile (256 rows x 64 k) for K-tile T into buffer BUF (4 glds)
#define STGA(BUF, T) do {                                                     \
    _Pragma("unroll")                                                         \
    for (int r_ = 0; r_ < 4; ++r_) {                                          \
      __builtin_amdgcn_global_load_lds(                                       \
        (const __attribute__((address_space(1))) void*)                       \
          (pA4[r_] + (size_t)(T) * 64),                                       \
        (__attribute__((address_space(3))) void*)                             \
          (AsB + (BUF) * 32768 + r_ * 8192 + tid * 16), 16, 0, 0);            \
    }                                                                         \
  } while (0)

// load next tile's 8 B-fragments into register set DST (coalesced 1KB each)
#define LDB(DST, TN) do {                                                     \
    _Pragma("unroll")                                                         \
    for (int fn_ = 0; fn_ < 2; ++fn_)                                         \
      _Pragma("unroll")                                                       \
      for (int kw_ = 0; kw_ < 4; ++kw_)                                       \
        DST[fn_ * 4 + kw_] = *(const short8*)(pB0 + (size_t)fn_ * 262144 +    \
            (size_t)(TN) * 4096 + kw_ * 1024 + l16);                          \
  } while (0)

// one K-tile phase: prefetch B(t+1)->BN, stage A(t+3)->BUFS, compute tile t
// from A-LDS buf BUF with B-regs BC.  One barrier per K-tile.
#define PHASE(T, BUF, BUFS, BC, BN) do {                                      \
    const int tn_ = ((T) + 1) & 63;                                           \
    const int ts_ = ((T) + 3) & 63;                                           \
    LDB(BN, tn_);                                                             \
    STGA(BUFS, ts_);                                                          \
    FENCE();                                                                  \
    PRIO1();                                                                  \
    _Pragma("unroll")                                                         \
    for (int kw_ = 0; kw_ < 4; ++kw_) {                                       \
      short8 aq0 = *(const short8*)(AsB + (BUF) * 32768 + aaddr[kw_]);        \
      short8 aq1 = *(const short8*)(AsB + (BUF) * 32768 + aaddr[kw_] + 4096); \
      short8 aq2 = *(const short8*)(AsB + (BUF) * 32768 + aaddr[kw_] + 8192); \
      short8 aq3 = *(const short8*)(AsB + (BUF) * 32768 + aaddr[kw_] + 12288);\
      acc[0][0] = __builtin_amdgcn_mfma_f32_32x32x16_bf16(aq0, BC[0 * 4 + kw_], acc[0][0], 0, 0, 0); \
      acc[1][0] = __builtin_amdgcn_mfma_f32_32x32x16_bf16(aq1, BC[0 * 4 + kw_], acc[1][0], 0, 0, 0); \
      acc[2][0] = __builtin_amdgcn_mfma_f32_32x32x16_bf16(aq2, BC[0 * 4 + kw_], acc[2][0], 0, 0, 0); \
      acc[3][0] = __builtin_amdgcn_mfma_f32_32x32x16_bf16(aq3, BC[0 * 4 + kw_], acc[3][0], 0, 0, 0); \
      acc[0][1] = __builtin_amdgcn_mfma_f32_32x32x16_bf16(aq0, BC[1 * 4 + kw_], acc[0][1], 0, 0, 0); \
      acc[1][1] = __builtin_amdgcn_mfma_f32_32x32x16_bf16(aq1, BC[1 * 4 + kw_], acc[1][1], 0, 0, 0); \
      acc[2][1] = __builtin_amdgcn_mfma_f32_32x32x16_bf16(aq2, BC[1 * 4 + kw_], acc[2][1], 0, 0, 0); \
      acc[3][1] = __builtin_amdgcn_mfma_f32_32x32x16_bf16(aq3, BC[1 * 4 + kw_], acc[3][1], 0, 0, 0); \
    }                                                                         \
    PRIO0(); FENCE();                                                         \
    VM4(); BAR(); FENCE();                                                    \
  } while (0)

__global__ __launch_bounds__(512, 2) void qgemm_bf16_3232(const u16* __restrict__ A,
                                                          const u16* __restrict__ Bp,
                                                          float* __restrict__ out) {
  __shared__ __align__(16) char AsB[4 * 32768];  // 4-deep A tiles [256][64] bf16, swizzled

  const int tid  = threadIdx.x;
  const int lane = tid & 63;
  const int wave = tid >> 6;
  const int wrow = wave >> 2;  // 0..1  -> 128 output rows
  const int wcol = wave & 3;   // 0..3  -> 64 output cols

  const int bid = blockIdx.x;
  const int sb = bid >> 4, li = bid & 15;
  const int mb = (sb & 7) * 4 + (li & 3);    // 0..31
  const int nb = (sb >> 3) * 4 + (li >> 2);  // 0..15
  const int m0 = mb * 256, n0 = nb * 256;

  // A staging bases (involution: LDS slot u holds global unit u^(row&7))
  const u16* pA4[4];
#pragma unroll
  for (int r = 0; r < 4; ++r) {
    const int row = r * 64 + (tid >> 3);
    const int su = (tid & 7) ^ ((tid >> 3) & 7);
    pA4[r] = A + (size_t)(m0 + row) * KDIM + su * 8;
  }

  // B base: fragment-linear Bp, this wave's n-block pair
  const int nblk0 = (n0 >> 5) + wcol * 2;
  const char* pB0 = (const char*)Bp + (size_t)nblk0 * 262144;
  const int l16 = lane * 16;

  // A fragment read addresses (swizzled): row = wrow*128 + fm*32 + (l&31),
  // unit = (kw*2 + (l>>5)) ^ (l&7)   [row&7 == l&7]
  const int rowbase = (wrow * 128 + (lane & 31)) * 128;
  const int hi = lane >> 5;
  const int lx = lane & 7;
  int aaddr[4];
#pragma unroll
  for (int kw = 0; kw < 4; ++kw)
    aaddr[kw] = rowbase + (((kw * 2 + hi) ^ lx) << 4);

  f32x16 acc[4][2];
#pragma unroll
  for (int i = 0; i < 4; ++i)
#pragma unroll
    for (int j = 0; j < 2; ++j)
      acc[i][j] = (f32x16)(0.f);

  short8 bA[8], bB[8];

  // ---- prologue: B(0) (oldest), A(0),A(1),A(2); vmcnt(8) forces B(0)+A(0) ----
  LDB(bA, 0);
  STGA(0, 0);
  STGA(1, 1);
  STGA(2, 2);
  asm volatile("s_waitcnt vmcnt(8)" ::: "memory");
  BAR(); FENCE();

  // ---- main loop: 16 iters x 4 K-tiles; buf = t&3 (compile-time per slot) ----
  for (int it = 0; it < 16; ++it) {
    const int tb = it * 4;
    PHASE(tb + 0, 0, 3, bA, bB);
    PHASE(tb + 1, 1, 0, bB, bA);
    PHASE(tb + 2, 2, 1, bA, bB);
    PHASE(tb + 3, 3, 2, bB, bA);
  }

  asm volatile("s_waitcnt vmcnt(0)" ::: "memory");  // drain wrapped dead stages

  // ---- epilogue: 32x32 C/D layout col=lane&31, row=(reg&3)+8*(reg>>2)+4*(lane>>5) ----
#pragma unroll
  for (int fm = 0; fm < 4; ++fm) {
#pragma unroll
    for (int fn = 0; fn < 2; ++fn) {
      const f32x16 c = acc[fm][fn];
      const int gc = n0 + wcol * 64 + fn * 32 + (lane & 31);
      const int gr0 = m0 + wrow * 128 + fm * 32 + hi * 4;
#pragma unroll
      for (int rg = 0; rg < 16; ++rg) {
        const int gr = gr0 + (rg & 3) + 8 * (rg >> 2);
        out[(size_t)gr * NDIM + gc] = c[rg];
      }
    }
  }
}

// ---------------- fallback: fused f32-input kernel (r3, proven) ----------------
#define BM 128
#define BN 128
#define BK 64
#define NKT (KDIM / BK)
#define LDA 72
__global__ __launch_bounds__(256) void qgemm_fused_f32(
    const float* __restrict__ x, const int* __restrict__ qweight,
    const int* __restrict__ qzeros, const float* __restrict__ scales,
    float* __restrict__ out) {
  __shared__ __align__(16) short As[BM * LDA];
  __shared__ __align__(16) short Bs[BN * LDA];

  const int tid = threadIdx.x;
  const int lane = tid & 63;
  const int wave = tid >> 6;
  const int wr = wave >> 1, wc = wave & 1;
  const int bid = blockIdx.x;
  const int sb = bid >> 4, li = bid & 15;
  const int mb = (sb & 15) * 4 + (li & 3);
  const int nb = (sb >> 4) * 4 + (li >> 2);
  const int m0 = mb * BM, n0 = nb * BN;

  const int ncol = tid & 127;
  const int kp_base = (tid >> 7) * 4;
  const int n_g = n0 + ncol;
  const float s = scales[n_g];
  const int zw = qzeros[n_g >> 3];
  const int zp1 = ((zw >> ((n_g & 7) * 4)) & 0xF) + 1;
  const float sz = -(float)zp1 * s;

  const int arow0 = tid >> 3;
  const int acol = (tid & 7) * 8;
  const int* qwp = qweight + (size_t)kp_base * NDIM + n_g;

  f32x4 af[8];
  {
    const float* xf = x + (size_t)(m0 + arow0) * KDIM + acol;
#pragma unroll
    for (int g = 0; g < 4; ++g) {
      af[2 * g]     = *(const f32x4*)(xf + (size_t)g * 32 * KDIM);
      af[2 * g + 1] = *(const f32x4*)(xf + (size_t)g * 32 * KDIM + 4);
    }
  }
  int qw0 = qwp[0], qw1 = qwp[NDIM], qw2 = qwp[2 * NDIM], qw3 = qwp[3 * NDIM];

  f32x4 acc[4][4];
#pragma unroll
  for (int i = 0; i < 4; ++i)
#pragma unroll
    for (int j = 0; j < 4; ++j)
      acc[i][j] = (f32x4)(0.f);

  const int lr = lane & 15, kh = lane >> 4;

  for (int kt = 0; kt < NKT; ++kt) {
    __syncthreads();
#pragma unroll
    for (int g = 0; g < 4; ++g) {
      short8 v;
#pragma unroll
      for (int j = 0; j < 4; ++j) {
        v[j]     = (short)f2bf(af[2 * g][j]);
        v[4 + j] = (short)f2bf(af[2 * g + 1][j]);
      }
      *(short8*)&As[(arow0 + g * 32) * LDA + acol] = v;
    }
    {
      const int qq[4] = {qw0, qw1, qw2, qw3};
#pragma unroll
      for (int r = 0; r < 4; ++r) {
        const int w = qq[r];
        short8 v;
#pragma unroll
        for (int j = 0; j < 8; ++j)
          v[j] = (short)f2bf(fmaf((float)((w >> (4 * j)) & 0xF), s, sz));
        *(short8*)&Bs[ncol * LDA + (kp_base + r) * 8] = v;
      }
    }
    if (kt + 1 < NKT) {
      const float* xp = x + (size_t)(m0 + arow0) * KDIM + (size_t)(kt + 1) * BK + acol;
#pragma unroll
      for (int g = 0; g < 4; ++g) {
        af[2 * g]     = *(const f32x4*)(xp + (size_t)g * 32 * KDIM);
        af[2 * g + 1] = *(const f32x4*)(xp + (size_t)g * 32 * KDIM + 4);
      }
      const int* p = qwp + (size_t)(kt + 1) * 8 * NDIM;
      qw0 = p[0]; qw1 = p[NDIM]; qw2 = p[2 * NDIM]; qw3 = p[3 * NDIM];
    }
    __syncthreads();
#pragma unroll
    for (int ks = 0; ks < 2; ++ks) {
      const int kb = (ks * 4 + kh) * 8;
      short8 a[4], bb[4];
#pragma unroll
      for (int mf = 0; mf < 4; ++mf)
        a[mf] = *(const short8*)&As[(wr * 64 + mf * 16 + lr) * LDA + kb];
#pragma unroll
      for (int nf = 0; nf < 4; ++nf)
        bb[nf] = *(const short8*)&Bs[(wc * 64 + nf * 16 + lr) * LDA + kb];
#pragma unroll
      for (int mf = 0; mf < 4; ++mf)
#pragma unroll
        for (int nf = 0; nf < 4; ++nf)
          acc[mf][nf] = __builtin_amdgcn_mfma_f32_16x16x32_bf16(a[mf], bb[nf], acc[mf][nf], 0, 0, 0);
    }
  }
#pragma unroll
  for (int mf = 0; mf < 4; ++mf)
#pragma unroll
    for (int nf = 0; nf < 4; ++nf) {
      const f32x4 c = acc[mf][nf];
      const int gc = n0 + wc * 64 + nf * 16 + lr;
#pragma unroll
      for (int rg = 0; rg < 4; ++rg)
        out[(size_t)(m0 + wr * 64 + mf * 16 + kh * 4 + rg) * NDIM + gc] = c[rg];
    }
}

extern "C" void kernel_launch(void* const* d_in, const int* in_sizes, int n_in,
                              void* d_out, int out_size, void* d_ws, size_t ws_size,
                              hipStream_t stream) {
  const float* x      = (const float*)d_in[0];  // fp16 ref stored as f32 on device
  const int* qweight  = (const int*)d_in[2];    // [K/8][N] int32
  const int* qzeros   = (const int*)d_in[3];    // [1][N/8] int32
  const float* scales = (const float*)d_in[4];  // fp16 ref stored as f32
  float* out = (float*)d_out;

  const size_t xb_bytes = (size_t)MDIM * KDIM * 2;  // 64 MB
  const size_t wt_bytes = (size_t)NDIM * KDIM * 2;  // 32 MB

  if (ws_size >= xb_bytes + wt_bytes) {
    u16* xb = (u16*)d_ws;
    u16* wt = (u16*)((char*)d_ws + xb_bytes);
    cvt_x_kernel<<<2048, 256, 0, stream>>>(x, xb, MDIM * KDIM / 8);
    dequant_w_kernel<<<2048, 256, 0, stream>>>(qweight, qzeros, scales, wt);
    const int grid = (MDIM / 256) * (NDIM / 256);  // 512
    qgemm_bf16_3232<<<grid, 512, 0, stream>>>(xb, wt, out);
  } else {
    const int grid = (MDIM / BM) * (NDIM / BN);  // 2048
    qgemm_fused_f32<<<grid, 256, 0, stream>>>(x, qweight, qzeros, scales, out);
  }
}